// Round 9
// baseline (230.575 us; speedup 1.0000x reference)
//
#include <hip/hip_runtime.h>
#include <hip/hip_bf16.h>

typedef __hip_bfloat16 bf16;
typedef short v8s __attribute__((ext_vector_type(8)));
typedef float v4f __attribute__((ext_vector_type(4)));

#define S_ 2048
#define D_ 1024
#define H_ 16
#define HD_ 64

#define EXP2F(x) __builtin_amdgcn_exp2f(x)   /* v_exp_f32: 2^x on gfx950 */
#define NEG_BIG (-1.0e30f)
#define C2 0.1803368801111244f   /* (1/sqrt(64)) * log2(e), folded into Q */

#define GLDS16(g, l) __builtin_amdgcn_global_load_lds(                        \
    (const __attribute__((address_space(1))) unsigned int*)(g),               \
    (__attribute__((address_space(3))) unsigned int*)(l), 16, 0, 0)

static __device__ __forceinline__ unsigned short bf16_bits(bf16 h) {
    union { bf16 h; unsigned short u; } c; c.h = h; return c.u;
}
static __device__ __forceinline__ float bits2f(unsigned short u) {
    union { float f; unsigned int i; } c; c.i = ((unsigned int)u) << 16; return c.f;
}

static __device__ __forceinline__ v8s pack_bf16x8(const float4 a, const float4 b) {
    union { v8s v; unsigned short u[8]; } r;
    r.u[0] = bf16_bits(__float2bfloat16(a.x));
    r.u[1] = bf16_bits(__float2bfloat16(a.y));
    r.u[2] = bf16_bits(__float2bfloat16(a.z));
    r.u[3] = bf16_bits(__float2bfloat16(a.w));
    r.u[4] = bf16_bits(__float2bfloat16(b.x));
    r.u[5] = bf16_bits(__float2bfloat16(b.y));
    r.u[6] = bf16_bits(__float2bfloat16(b.z));
    r.u[7] = bf16_bits(__float2bfloat16(b.w));
    return r.v;
}

// ---------------------------------------------------------------------------
// fp32 -> bf16 conversion pre-pass
// ---------------------------------------------------------------------------
__global__ __launch_bounds__(256)
void cvt_bf16(const float* __restrict__ x,  const float* __restrict__ wq,
              const float* __restrict__ wk, const float* __restrict__ wv,
              const float* __restrict__ wo,
              bf16* __restrict__ xb,  bf16* __restrict__ wqb,
              bf16* __restrict__ wkb, bf16* __restrict__ wvb,
              bf16* __restrict__ wob)
{
    const int seg = blockIdx.y;
    const float* src; bf16* dst; int n;
    switch (seg) {
        case 0: src = x;  dst = xb;  n = 4096 * 1024; break;
        case 1: src = wq; dst = wqb; n = 1024 * 1024; break;
        case 2: src = wk; dst = wkb; n = 1024 * 1024; break;
        case 3: src = wv; dst = wvb; n = 1024 * 1024; break;
        default:src = wo; dst = wob; n = 1024 * 1024; break;
    }
    const int idx = (blockIdx.x * 256 + threadIdx.x) * 8;
    if (idx >= n) return;
    *(v8s*)&dst[idx] = pack_bf16x8(*(const float4*)&src[idx],
                                   *(const float4*)&src[idx + 4]);
}

// ---------------------------------------------------------------------------
// FAST NT GEMM (m97-style): bf16 inputs, global_load_lds width-16 staging.
// ---------------------------------------------------------------------------
__global__ __launch_bounds__(256)
void gemm_qkv_f(const bf16* __restrict__ xb, const bf16* __restrict__ wqb,
                const bf16* __restrict__ wkb, const bf16* __restrict__ wvb,
                bf16* __restrict__ qd, bf16* __restrict__ kd, bf16* __restrict__ vtd)
{
    const int mode = blockIdx.z;
    const bf16* __restrict__ W = (mode == 0) ? wqb : (mode == 1) ? wkb : wvb;
    const int m0 = blockIdx.x * 128;
    const int n0 = blockIdx.y * 128;
    __shared__ bf16 As[128 * 32];
    __shared__ bf16 Bs[128 * 32];
    const int t    = threadIdx.x;
    const int lane = t & 63, w = t >> 6;
    const int wr = w >> 1, wc = w & 1;
    const int l15 = lane & 15, quad = lane >> 4;
    const int r16 = lane >> 2, c8 = (lane & 3) * 8;
    v4f acc[4][4] = {};

    const bf16* ga = &xb[(m0 + w*16 + r16) * 1024 + c8];
    const bf16* gb = &W [(n0 + w*16 + r16) * 1024 + c8];
    bf16* la0 = &As[w * 16 * 32];
    bf16* la1 = &As[(64 + w * 16) * 32];
    bf16* lb0 = &Bs[w * 16 * 32];
    bf16* lb1 = &Bs[(64 + w * 16) * 32];

    for (int k0 = 0; k0 < 1024; k0 += 32) {
        __syncthreads();
        GLDS16(ga + k0,             la0);
        GLDS16(ga + k0 + 64 * 1024, la1);
        GLDS16(gb + k0,             lb0);
        GLDS16(gb + k0 + 64 * 1024, lb1);
        __syncthreads();
        v8s a[4], b[4];
#pragma unroll
        for (int mt = 0; mt < 4; mt++) a[mt] = *(const v8s*)&As[(wr*64 + mt*16 + l15)*32 + quad*8];
#pragma unroll
        for (int nt = 0; nt < 4; nt++) b[nt] = *(const v8s*)&Bs[(wc*64 + nt*16 + l15)*32 + quad*8];
#pragma unroll
        for (int mt = 0; mt < 4; mt++)
#pragma unroll
            for (int nt = 0; nt < 4; nt++)
                acc[mt][nt] = __builtin_amdgcn_mfma_f32_16x16x32_bf16(a[mt], b[nt], acc[mt][nt], 0, 0, 0);
    }

    const float qscale = (mode == 0) ? C2 : 1.0f;
#pragma unroll
    for (int mt = 0; mt < 4; mt++) {
        const int mb = m0 + wr*64 + mt*16 + quad*4;
        const int b_ = mb >> 11, s = mb & 2047;
#pragma unroll
        for (int nt = 0; nt < 4; nt++) {
            const int n = n0 + wc*64 + nt*16 + l15;
            const int h = n >> 6, d = n & 63;
            if (mode == 2) {
                unsigned int lo = (unsigned int)bf16_bits(__float2bfloat16(acc[mt][nt][0]))
                                | ((unsigned int)bf16_bits(__float2bfloat16(acc[mt][nt][1])) << 16);
                unsigned int hi = (unsigned int)bf16_bits(__float2bfloat16(acc[mt][nt][2]))
                                | ((unsigned int)bf16_bits(__float2bfloat16(acc[mt][nt][3])) << 16);
                uint2 pv; pv.x = lo; pv.y = hi;
                *(uint2*)&vtd[((b_*H_ + h)*HD_ + d)*S_ + s] = pv;
            } else {
                bf16* __restrict__ dst = (mode == 0) ? qd : kd;
#pragma unroll
                for (int r = 0; r < 4; r++)
                    dst[((b_*H_ + h)*S_ + (s + r))*HD_ + d] = __float2bfloat16(acc[mt][nt][r] * qscale);
            }
        }
    }
}

__global__ __launch_bounds__(256)
void gemm_out_f(const bf16* __restrict__ ctx, const bf16* __restrict__ wob,
                const float* __restrict__ bo, float* __restrict__ out)
{
    const int m0 = blockIdx.x * 128;
    const int n0 = blockIdx.y * 128;
    __shared__ bf16 As[128 * 32];
    __shared__ bf16 Bs[128 * 32];
    const int t    = threadIdx.x;
    const int lane = t & 63, w = t >> 6;
    const int wr = w >> 1, wc = w & 1;
    const int l15 = lane & 15, quad = lane >> 4;
    const int r16 = lane >> 2, c8 = (lane & 3) * 8;
    v4f acc[4][4] = {};

    const bf16* ga = &ctx[(m0 + w*16 + r16) * 1024 + c8];
    const bf16* gb = &wob[(n0 + w*16 + r16) * 1024 + c8];
    bf16* la0 = &As[w * 16 * 32];
    bf16* la1 = &As[(64 + w * 16) * 32];
    bf16* lb0 = &Bs[w * 16 * 32];
    bf16* lb1 = &Bs[(64 + w * 16) * 32];

    for (int k0 = 0; k0 < 1024; k0 += 32) {
        __syncthreads();
        GLDS16(ga + k0,             la0);
        GLDS16(ga + k0 + 64 * 1024, la1);
        GLDS16(gb + k0,             lb0);
        GLDS16(gb + k0 + 64 * 1024, lb1);
        __syncthreads();
        v8s a[4], b[4];
#pragma unroll
        for (int mt = 0; mt < 4; mt++) a[mt] = *(const v8s*)&As[(wr*64 + mt*16 + l15)*32 + quad*8];
#pragma unroll
        for (int nt = 0; nt < 4; nt++) b[nt] = *(const v8s*)&Bs[(wc*64 + nt*16 + l15)*32 + quad*8];
#pragma unroll
        for (int mt = 0; mt < 4; mt++)
#pragma unroll
            for (int nt = 0; nt < 4; nt++)
                acc[mt][nt] = __builtin_amdgcn_mfma_f32_16x16x32_bf16(a[mt], b[nt], acc[mt][nt], 0, 0, 0);
    }

#pragma unroll
    for (int mt = 0; mt < 4; mt++) {
        const int mb = m0 + wr*64 + mt*16 + quad*4;
#pragma unroll
        for (int nt = 0; nt < 4; nt++) {
            const int n = n0 + wc*64 + nt*16 + l15;
            const float bias = bo[n];
#pragma unroll
            for (int r = 0; r < 4; r++)
                out[(mb + r)*1024 + n] = acc[mt][nt][r] + bias;
        }
    }
}

// ---------------------------------------------------------------------------
// FALLBACK GEMMs (fp32 inputs, cvt fused in staging)
// ---------------------------------------------------------------------------
__global__ __launch_bounds__(256)
void gemm_qkv(const float* __restrict__ x, const float* __restrict__ Wq,
              const float* __restrict__ Wk, const float* __restrict__ Wv,
              bf16* __restrict__ qd, bf16* __restrict__ kd, bf16* __restrict__ vtd)
{
    const int mode = blockIdx.z;
    const float* __restrict__ W = (mode == 0) ? Wq : (mode == 1) ? Wk : Wv;
    const int m0 = blockIdx.x * 128;
    const int n0 = blockIdx.y * 128;
    __shared__ bf16 As[128 * 40];
    __shared__ bf16 Bs[128 * 40];
    const int t    = threadIdx.x;
    const int lane = t & 63, w = t >> 6;
    const int wr = w >> 1, wc = w & 1;
    const int l15 = lane & 15, quad = lane >> 4;
    const int srow = t >> 2, scol = (t & 3) * 8;
    v4f acc[4][4] = {};

    for (int k0 = 0; k0 < 1024; k0 += 32) {
        __syncthreads();
        {
            const float* pa = &x[(m0 + srow) * 1024 + k0 + scol];
            *(v8s*)&As[srow*40 + scol] = pack_bf16x8(*(const float4*)pa, *(const float4*)(pa + 4));
            const float* pa2 = pa + 64 * 1024;
            *(v8s*)&As[(srow+64)*40 + scol] = pack_bf16x8(*(const float4*)pa2, *(const float4*)(pa2 + 4));
            const float* pb = &W[(n0 + srow) * 1024 + k0 + scol];
            *(v8s*)&Bs[srow*40 + scol] = pack_bf16x8(*(const float4*)pb, *(const float4*)(pb + 4));
            const float* pb2 = pb + 64 * 1024;
            *(v8s*)&Bs[(srow+64)*40 + scol] = pack_bf16x8(*(const float4*)pb2, *(const float4*)(pb2 + 4));
        }
        __syncthreads();
        v8s a[4], b[4];
#pragma unroll
        for (int mt = 0; mt < 4; mt++) a[mt] = *(const v8s*)&As[(wr*64 + mt*16 + l15)*40 + quad*8];
#pragma unroll
        for (int nt = 0; nt < 4; nt++) b[nt] = *(const v8s*)&Bs[(wc*64 + nt*16 + l15)*40 + quad*8];
#pragma unroll
        for (int mt = 0; mt < 4; mt++)
#pragma unroll
            for (int nt = 0; nt < 4; nt++)
                acc[mt][nt] = __builtin_amdgcn_mfma_f32_16x16x32_bf16(a[mt], b[nt], acc[mt][nt], 0, 0, 0);
    }

    const float qscale = (mode == 0) ? C2 : 1.0f;
#pragma unroll
    for (int mt = 0; mt < 4; mt++) {
        const int mb = m0 + wr*64 + mt*16 + quad*4;
        const int b_ = mb >> 11, s = mb & 2047;
#pragma unroll
        for (int nt = 0; nt < 4; nt++) {
            const int n = n0 + wc*64 + nt*16 + l15;
            const int h = n >> 6, d = n & 63;
            if (mode == 2) {
                unsigned int lo = (unsigned int)bf16_bits(__float2bfloat16(acc[mt][nt][0]))
                                | ((unsigned int)bf16_bits(__float2bfloat16(acc[mt][nt][1])) << 16);
                unsigned int hi = (unsigned int)bf16_bits(__float2bfloat16(acc[mt][nt][2]))
                                | ((unsigned int)bf16_bits(__float2bfloat16(acc[mt][nt][3])) << 16);
                uint2 pv; pv.x = lo; pv.y = hi;
                *(uint2*)&vtd[((b_*H_ + h)*HD_ + d)*S_ + s] = pv;
            } else {
                bf16* __restrict__ dst = (mode == 0) ? qd : kd;
#pragma unroll
                for (int r = 0; r < 4; r++)
                    dst[((b_*H_ + h)*S_ + (s + r))*HD_ + d] = __float2bfloat16(acc[mt][nt][r] * qscale);
            }
        }
    }
}

__global__ __launch_bounds__(256)
void gemm_out(const bf16* __restrict__ ctx, const float* __restrict__ Wo,
              const float* __restrict__ bo, float* __restrict__ out)
{
    const int m0 = blockIdx.x * 128;
    const int n0 = blockIdx.y * 128;
    __shared__ bf16 As[128 * 40];
    __shared__ bf16 Bs[128 * 40];
    const int t    = threadIdx.x;
    const int lane = t & 63, w = t >> 6;
    const int wr = w >> 1, wc = w & 1;
    const int l15 = lane & 15, quad = lane >> 4;
    const int srow = t >> 2, scol = (t & 3) * 8;
    v4f acc[4][4] = {};

    for (int k0 = 0; k0 < 1024; k0 += 32) {
        __syncthreads();
        {
            *(v8s*)&As[srow*40 + scol]      = *(const v8s*)&ctx[(m0+srow)*1024 + k0 + scol];
            *(v8s*)&As[(srow+64)*40 + scol] = *(const v8s*)&ctx[(m0+srow+64)*1024 + k0 + scol];
            const float* pb = &Wo[(n0 + srow) * 1024 + k0 + scol];
            *(v8s*)&Bs[srow*40 + scol] = pack_bf16x8(*(const float4*)pb, *(const float4*)(pb + 4));
            const float* pb2 = pb + 64 * 1024;
            *(v8s*)&Bs[(srow+64)*40 + scol] = pack_bf16x8(*(const float4*)pb2, *(const float4*)(pb2 + 4));
        }
        __syncthreads();
        v8s a[4], b[4];
#pragma unroll
        for (int mt = 0; mt < 4; mt++) a[mt] = *(const v8s*)&As[(wr*64 + mt*16 + l15)*40 + quad*8];
#pragma unroll
        for (int nt = 0; nt < 4; nt++) b[nt] = *(const v8s*)&Bs[(wc*64 + nt*16 + l15)*40 + quad*8];
#pragma unroll
        for (int mt = 0; mt < 4; mt++)
#pragma unroll
            for (int nt = 0; nt < 4; nt++)
                acc[mt][nt] = __builtin_amdgcn_mfma_f32_16x16x32_bf16(a[mt], b[nt], acc[mt][nt], 0, 0, 0);
    }

#pragma unroll
    for (int mt = 0; mt < 4; mt++) {
        const int mb = m0 + wr*64 + mt*16 + quad*4;
#pragma unroll
        for (int nt = 0; nt < 4; nt++) {
            const int n = n0 + wc*64 + nt*16 + l15;
            const float bias = bo[n];
#pragma unroll
            for (int r = 0; r < 4; r++)
                out[(mb + r)*1024 + n] = acc[mt][nt][r] + bias;
        }
    }
}

// ---------------------------------------------------------------------------
// Causal flash attention v4: fixed-offset exp2 softmax (linear -> split-K
// partials just add). gridDim.z==2: each z handles half the k-tiles, writes
// unnormalized bf16 partial O + per-row fp32 l. gridDim.z==1: normalized ctx.
// ---------------------------------------------------------------------------
__global__ __launch_bounds__(256)
void flash_attn(const bf16* __restrict__ qd, const bf16* __restrict__ kd,
                const bf16* __restrict__ vtd, bf16* __restrict__ outp,
                float* __restrict__ lsum)
{
    const int qb = 15 - blockIdx.x;
    const int bh = blockIdx.y;
    const int split = blockIdx.z;
    const bool dosplit = (gridDim.z == 2);
    const int t = threadIdx.x;
    const int lane = t & 63, w = t >> 6;
    const int l15 = lane & 15, quad = lane >> 4;
    const int q0 = qb * 128;

    const int tbeg = dosplit ? split * (qb + 1) : 0;
    const int tend = dosplit ? tbeg + qb + 1 : 2 * qb + 2;

    __shared__ bf16 Ks[2][64 * 72];
    __shared__ bf16 Vs[2][64 * 72];
    __shared__ bf16 Pl[4][16 * 72];

    const int mrow0 = q0 + w * 16;
    const int mrow1 = q0 + 64 + w * 16;

    v8s qf[2][2];
#pragma unroll
    for (int mt = 0; mt < 2; mt++) {
        const bf16* qb_ = qd + (bh*S_ + (mt ? mrow1 : mrow0) + l15) * HD_;
        qf[mt][0] = *(const v8s*)(qb_ + quad*8);
        qf[mt][1] = *(const v8s*)(qb_ + 32 + quad*8);
    }

    v4f o[2][4] = {};
    float ps[2][4] = {};

    const int rowlo = t >> 3, col8 = (t & 7) * 8;

    int c0 = tbeg * 64;
    v8s pk0 = *(const v8s*)&kd[(bh*S_ + c0 + rowlo)*HD_ + col8];
    v8s pk1 = *(const v8s*)&kd[(bh*S_ + c0 + rowlo + 32)*HD_ + col8];
    v8s pv0 = *(const v8s*)&vtd[(bh*HD_ + rowlo)*S_ + c0 + col8];
    v8s pv1 = *(const v8s*)&vtd[(bh*HD_ + rowlo + 32)*S_ + c0 + col8];

    for (int it = tbeg; it < tend; ++it) {
        c0 = it * 64;
        bf16* Kb = &Ks[it & 1][0];
        bf16* Vb = &Vs[it & 1][0];
        *(v8s*)&Kb[rowlo*72 + col8]      = pk0;
        *(v8s*)&Kb[(rowlo+32)*72 + col8] = pk1;
        *(v8s*)&Vb[rowlo*72 + col8]      = pv0;
        *(v8s*)&Vb[(rowlo+32)*72 + col8] = pv1;
        const int cn = (it + 1 < tend) ? c0 + 64 : tbeg * 64;
        pk0 = *(const v8s*)&kd[(bh*S_ + cn + rowlo)*HD_ + col8];
        pk1 = *(const v8s*)&kd[(bh*S_ + cn + rowlo + 32)*HD_ + col8];
        pv0 = *(const v8s*)&vtd[(bh*HD_ + rowlo)*S_ + cn + col8];
        pv1 = *(const v8s*)&vtd[(bh*HD_ + rowlo + 32)*S_ + cn + col8];
        __syncthreads();

        if (c0 <= mrow1 + 15) {
            v8s kf[4][2];
#pragma unroll
            for (int kt = 0; kt < 4; kt++) {
                kf[kt][0] = *(const v8s*)&Kb[(kt*16 + l15)*72 + quad*8];
                kf[kt][1] = *(const v8s*)&Kb[(kt*16 + l15)*72 + 32 + quad*8];
            }
            v8s vf[4][2];
#pragma unroll
            for (int dt = 0; dt < 4; dt++) {
                vf[dt][0] = *(const v8s*)&Vs[it & 1][(dt*16 + l15)*72 + quad*8];
                vf[dt][1] = *(const v8s*)&Vs[it & 1][(dt*16 + l15)*72 + 32 + quad*8];
            }

#pragma unroll
            for (int mt = 0; mt < 2; mt++) {
                const int mr = mt ? mrow1 : mrow0;
                if (c0 > mr + 15) continue;
                v4f sc[4] = {};
#pragma unroll
                for (int kt = 0; kt < 4; kt++) {
                    sc[kt] = __builtin_amdgcn_mfma_f32_16x16x32_bf16(qf[mt][0], kf[kt][0], sc[kt], 0, 0, 0);
                    sc[kt] = __builtin_amdgcn_mfma_f32_16x16x32_bf16(qf[mt][1], kf[kt][1], sc[kt], 0, 0, 0);
                }
                const bool full = (c0 + 63 <= mr);
#pragma unroll
                for (int r = 0; r < 4; r++) {
                    const int qg = mr + quad*4 + r;
#pragma unroll
                    for (int kt = 0; kt < 4; kt++) {
                        float s = sc[kt][r];
                        if (!full) {
                            const int kg = c0 + kt*16 + l15;
                            s = (kg <= qg) ? s : NEG_BIG;
                        }
                        const float p = EXP2F(s);
                        sc[kt][r] = p;
                        ps[mt][r] += p;
                    }
                }
                bf16* pw = &Pl[w][0];
#pragma unroll
                for (int kt = 0; kt < 4; kt++)
#pragma unroll
                    for (int r = 0; r < 4; r++)
                        pw[(quad*4 + r)*72 + kt*16 + l15] = __float2bfloat16(sc[kt][r]);
                v8s pf0 = *(const v8s*)&pw[l15*72 + quad*8];
                v8s pf1 = *(const v8s*)&pw[l15*72 + 32 + quad*8];
#pragma unroll
                for (int dt = 0; dt < 4; dt++) {
                    o[mt][dt] = __builtin_amdgcn_mfma_f32_16x16x32_bf16(pf0, vf[dt][0], o[mt][dt], 0, 0, 0);
                    o[mt][dt] = __builtin_amdgcn_mfma_f32_16x16x32_bf16(pf1, vf[dt][1], o[mt][dt], 0, 0, 0);
                }
            }
        }
    }

    const int b_ = bh >> 4, h = bh & 15;
    bf16* __restrict__ po = outp + (size_t)split * (4 * 1024 * 1024);
    float* __restrict__ ls = lsum + split * (32 * S_);
#pragma unroll
    for (int mt = 0; mt < 2; mt++) {
        const int mr = mt ? mrow1 : mrow0;
#pragma unroll
        for (int r = 0; r < 4; r++) {
            float l = ps[mt][r];
#pragma unroll
            for (int off = 1; off < 16; off <<= 1) l += __shfl_xor(l, off);
            const int qg = mr + quad*4 + r;
            if (!dosplit) {
                const float linv = 1.0f / l;
#pragma unroll
                for (int dt = 0; dt < 4; dt++)
                    outp[(b_*S_ + qg)*D_ + h*HD_ + dt*16 + l15] = __float2bfloat16(o[mt][dt][r] * linv);
            } else {
                if (l15 == 0) ls[bh*S_ + qg] = l;
#pragma unroll
                for (int dt = 0; dt < 4; dt++)
                    po[(b_*S_ + qg)*D_ + h*HD_ + dt*16 + l15] = __float2bfloat16(o[mt][dt][r]);
            }
        }
    }
}

// ---------------------------------------------------------------------------
// split-K combine: ctx = (O0 + O1) / (l0 + l1)
// ---------------------------------------------------------------------------
__global__ __launch_bounds__(256)
void combine_k(const bf16* __restrict__ po, const float* __restrict__ lsum,
               bf16* __restrict__ ctx)
{
    const int idx = (blockIdx.x * 256 + threadIdx.x) * 8;   // over 4 Mi elems
    const int row = idx >> 10;                              // b*S+s
    const int h = (idx & 1023) >> 6;
    const int b = row >> 11, s = row & 2047;
    const int bh = b * 16 + h;
    const float linv = 1.0f / (lsum[bh*S_ + s] + lsum[32*S_ + bh*S_ + s]);
    union { v8s v; unsigned short u[8]; } a, c, r;
    a.v = *(const v8s*)&po[idx];
    c.v = *(const v8s*)&po[4*1024*1024 + idx];
#pragma unroll
    for (int j = 0; j < 8; j++)
        r.u[j] = bf16_bits(__float2bfloat16((bits2f(a.u[j]) + bits2f(c.u[j])) * linv));
    *(v8s*)&ctx[idx] = r.v;
}

extern "C" void kernel_launch(void* const* d_in, const int* in_sizes, int n_in,
                              void* d_out, int out_size, void* d_ws, size_t ws_size,
                              hipStream_t stream) {
    const float* x  = (const float*)d_in[0];
    const float* Wq = (const float*)d_in[1];
    const float* Wk = (const float*)d_in[2];
    const float* Wv = (const float*)d_in[3];
    const float* Wo = (const float*)d_in[4];
    const float* bo = (const float*)d_in[5];
    float* out = (float*)d_out;

    const size_t SEG = (size_t)2 * H_ * S_ * HD_;      // 4 Mi bf16 elems = 8 MB
    bf16* qd  = (bf16*)d_ws;
    bf16* kd  = qd  + SEG;
    bf16* vtd = kd  + SEG;
    bf16* xc  = vtd + SEG;                             // x-bf16, later ctx
    bf16* wqb = xc + SEG;
    bf16* wkb = wqb + 1024 * 1024;
    bf16* wvb = wkb + 1024 * 1024;
    bf16* wob = wvb + 1024 * 1024;
    bf16* po  = wob + 1024 * 1024;                     // 2 x 4 Mi elems = 16 MB
    float* lsum = (float*)(po + 2 * SEG);              // 2 x 64 Ki floats

    const size_t need_fast  = (4 * SEG + 4 * 1024 * 1024) * sizeof(bf16);            // 40 MB
    const size_t need_split = need_fast + 2 * SEG * sizeof(bf16) + 2 * 32 * S_ * sizeof(float);

    if (ws_size >= need_split) {
        cvt_bf16<<<dim3(2048, 5), 256, 0, stream>>>(x, Wq, Wk, Wv, Wo,
                                                    xc, wqb, wkb, wvb, wob);
        gemm_qkv_f<<<dim3(32, 8, 3), 256, 0, stream>>>(xc, wqb, wkb, wvb, qd, kd, vtd);
        flash_attn<<<dim3(16, 32, 2), 256, 0, stream>>>(qd, kd, vtd, po, lsum);
        combine_k<<<dim3(2048), 256, 0, stream>>>(po, lsum, xc);        // xc = ctx
        gemm_out_f<<<dim3(32, 8), 256, 0, stream>>>(xc, wob, bo, out);
    } else if (ws_size >= need_fast) {
        cvt_bf16<<<dim3(2048, 5), 256, 0, stream>>>(x, Wq, Wk, Wv, Wo,
                                                    xc, wqb, wkb, wvb, wob);
        gemm_qkv_f<<<dim3(32, 8, 3), 256, 0, stream>>>(xc, wqb, wkb, wvb, qd, kd, vtd);
        flash_attn<<<dim3(16, 32, 1), 256, 0, stream>>>(qd, kd, vtd, xc, lsum);
        gemm_out_f<<<dim3(32, 8), 256, 0, stream>>>(xc, wob, bo, out);
    } else {
        gemm_qkv<<<dim3(32, 8, 3), 256, 0, stream>>>(x, Wq, Wk, Wv, qd, kd, vtd);
        flash_attn<<<dim3(16, 32, 1), 256, 0, stream>>>(qd, kd, vtd, xc, (float*)xc);
        gemm_out<<<dim3(32, 8), 256, 0, stream>>>(xc, Wo, bo, out);
    }
}

// Round 10
// 230.269 us; speedup vs baseline: 1.0013x; 1.0013x over previous
//
#include <hip/hip_runtime.h>
#include <hip/hip_bf16.h>

typedef __hip_bfloat16 bf16;
typedef short v8s __attribute__((ext_vector_type(8)));
typedef float v4f __attribute__((ext_vector_type(4)));

#define S_ 2048
#define D_ 1024
#define H_ 16
#define HD_ 64

#define EXP2F(x) __builtin_amdgcn_exp2f(x)   /* v_exp_f32: 2^x on gfx950 */
#define NEG_BIG (-1.0e30f)
#define C2 0.1803368801111244f   /* (1/sqrt(64)) * log2(e), folded into Q */

#define GLDS16(g, l) __builtin_amdgcn_global_load_lds(                        \
    (const __attribute__((address_space(1))) unsigned int*)(g),               \
    (__attribute__((address_space(3))) unsigned int*)(l), 16, 0, 0)

static __device__ __forceinline__ unsigned short bf16_bits(bf16 h) {
    union { bf16 h; unsigned short u; } c; c.h = h; return c.u;
}
static __device__ __forceinline__ float bits2f(unsigned short u) {
    union { float f; unsigned int i; } c; c.i = ((unsigned int)u) << 16; return c.f;
}

static __device__ __forceinline__ v8s pack_bf16x8(const float4 a, const float4 b) {
    union { v8s v; unsigned short u[8]; } r;
    r.u[0] = bf16_bits(__float2bfloat16(a.x));
    r.u[1] = bf16_bits(__float2bfloat16(a.y));
    r.u[2] = bf16_bits(__float2bfloat16(a.z));
    r.u[3] = bf16_bits(__float2bfloat16(a.w));
    r.u[4] = bf16_bits(__float2bfloat16(b.x));
    r.u[5] = bf16_bits(__float2bfloat16(b.y));
    r.u[6] = bf16_bits(__float2bfloat16(b.z));
    r.u[7] = bf16_bits(__float2bfloat16(b.w));
    return r.v;
}

// ---------------------------------------------------------------------------
// fp32 -> bf16 conversion pre-pass
// ---------------------------------------------------------------------------
__global__ __launch_bounds__(256)
void cvt_bf16(const float* __restrict__ x,  const float* __restrict__ wq,
              const float* __restrict__ wk, const float* __restrict__ wv,
              const float* __restrict__ wo,
              bf16* __restrict__ xb,  bf16* __restrict__ wqb,
              bf16* __restrict__ wkb, bf16* __restrict__ wvb,
              bf16* __restrict__ wob)
{
    const int seg = blockIdx.y;
    const float* src; bf16* dst; int n;
    switch (seg) {
        case 0: src = x;  dst = xb;  n = 4096 * 1024; break;
        case 1: src = wq; dst = wqb; n = 1024 * 1024; break;
        case 2: src = wk; dst = wkb; n = 1024 * 1024; break;
        case 3: src = wv; dst = wvb; n = 1024 * 1024; break;
        default:src = wo; dst = wob; n = 1024 * 1024; break;
    }
    const int idx = (blockIdx.x * 256 + threadIdx.x) * 8;
    if (idx >= n) return;
    *(v8s*)&dst[idx] = pack_bf16x8(*(const float4*)&src[idx],
                                   *(const float4*)&src[idx + 4]);
}

// ---------------------------------------------------------------------------
// FAST NT GEMM (m97-style): bf16 inputs, global_load_lds width-16 staging.
// ---------------------------------------------------------------------------
__global__ __launch_bounds__(256)
void gemm_qkv_f(const bf16* __restrict__ xb, const bf16* __restrict__ wqb,
                const bf16* __restrict__ wkb, const bf16* __restrict__ wvb,
                bf16* __restrict__ qd, bf16* __restrict__ kd, bf16* __restrict__ vtd)
{
    const int mode = blockIdx.z;
    const bf16* __restrict__ W = (mode == 0) ? wqb : (mode == 1) ? wkb : wvb;
    const int m0 = blockIdx.x * 128;
    const int n0 = blockIdx.y * 128;
    __shared__ bf16 As[128 * 32];
    __shared__ bf16 Bs[128 * 32];
    const int t    = threadIdx.x;
    const int lane = t & 63, w = t >> 6;
    const int wr = w >> 1, wc = w & 1;
    const int l15 = lane & 15, quad = lane >> 4;
    const int r16 = lane >> 2, c8 = (lane & 3) * 8;
    v4f acc[4][4] = {};

    const bf16* ga = &xb[(m0 + w*16 + r16) * 1024 + c8];
    const bf16* gb = &W [(n0 + w*16 + r16) * 1024 + c8];
    bf16* la0 = &As[w * 16 * 32];
    bf16* la1 = &As[(64 + w * 16) * 32];
    bf16* lb0 = &Bs[w * 16 * 32];
    bf16* lb1 = &Bs[(64 + w * 16) * 32];

    for (int k0 = 0; k0 < 1024; k0 += 32) {
        __syncthreads();
        GLDS16(ga + k0,             la0);
        GLDS16(ga + k0 + 64 * 1024, la1);
        GLDS16(gb + k0,             lb0);
        GLDS16(gb + k0 + 64 * 1024, lb1);
        __syncthreads();
        v8s a[4], b[4];
#pragma unroll
        for (int mt = 0; mt < 4; mt++) a[mt] = *(const v8s*)&As[(wr*64 + mt*16 + l15)*32 + quad*8];
#pragma unroll
        for (int nt = 0; nt < 4; nt++) b[nt] = *(const v8s*)&Bs[(wc*64 + nt*16 + l15)*32 + quad*8];
#pragma unroll
        for (int mt = 0; mt < 4; mt++)
#pragma unroll
            for (int nt = 0; nt < 4; nt++)
                acc[mt][nt] = __builtin_amdgcn_mfma_f32_16x16x32_bf16(a[mt], b[nt], acc[mt][nt], 0, 0, 0);
    }

    const float qscale = (mode == 0) ? C2 : 1.0f;
#pragma unroll
    for (int mt = 0; mt < 4; mt++) {
        const int mb = m0 + wr*64 + mt*16 + quad*4;
        const int b_ = mb >> 11, s = mb & 2047;
#pragma unroll
        for (int nt = 0; nt < 4; nt++) {
            const int n = n0 + wc*64 + nt*16 + l15;
            const int h = n >> 6, d = n & 63;
            if (mode == 2) {
                unsigned int lo = (unsigned int)bf16_bits(__float2bfloat16(acc[mt][nt][0]))
                                | ((unsigned int)bf16_bits(__float2bfloat16(acc[mt][nt][1])) << 16);
                unsigned int hi = (unsigned int)bf16_bits(__float2bfloat16(acc[mt][nt][2]))
                                | ((unsigned int)bf16_bits(__float2bfloat16(acc[mt][nt][3])) << 16);
                uint2 pv; pv.x = lo; pv.y = hi;
                *(uint2*)&vtd[((b_*H_ + h)*HD_ + d)*S_ + s] = pv;
            } else {
                bf16* __restrict__ dst = (mode == 0) ? qd : kd;
#pragma unroll
                for (int r = 0; r < 4; r++)
                    dst[((b_*H_ + h)*S_ + (s + r))*HD_ + d] = __float2bfloat16(acc[mt][nt][r] * qscale);
            }
        }
    }
}

__global__ __launch_bounds__(256)
void gemm_out_f(const bf16* __restrict__ ctx, const bf16* __restrict__ wob,
                const float* __restrict__ bo, float* __restrict__ out)
{
    const int m0 = blockIdx.x * 128;
    const int n0 = blockIdx.y * 128;
    __shared__ bf16 As[128 * 32];
    __shared__ bf16 Bs[128 * 32];
    const int t    = threadIdx.x;
    const int lane = t & 63, w = t >> 6;
    const int wr = w >> 1, wc = w & 1;
    const int l15 = lane & 15, quad = lane >> 4;
    const int r16 = lane >> 2, c8 = (lane & 3) * 8;
    v4f acc[4][4] = {};

    const bf16* ga = &ctx[(m0 + w*16 + r16) * 1024 + c8];
    const bf16* gb = &wob[(n0 + w*16 + r16) * 1024 + c8];
    bf16* la0 = &As[w * 16 * 32];
    bf16* la1 = &As[(64 + w * 16) * 32];
    bf16* lb0 = &Bs[w * 16 * 32];
    bf16* lb1 = &Bs[(64 + w * 16) * 32];

    for (int k0 = 0; k0 < 1024; k0 += 32) {
        __syncthreads();
        GLDS16(ga + k0,             la0);
        GLDS16(ga + k0 + 64 * 1024, la1);
        GLDS16(gb + k0,             lb0);
        GLDS16(gb + k0 + 64 * 1024, lb1);
        __syncthreads();
        v8s a[4], b[4];
#pragma unroll
        for (int mt = 0; mt < 4; mt++) a[mt] = *(const v8s*)&As[(wr*64 + mt*16 + l15)*32 + quad*8];
#pragma unroll
        for (int nt = 0; nt < 4; nt++) b[nt] = *(const v8s*)&Bs[(wc*64 + nt*16 + l15)*32 + quad*8];
#pragma unroll
        for (int mt = 0; mt < 4; mt++)
#pragma unroll
            for (int nt = 0; nt < 4; nt++)
                acc[mt][nt] = __builtin_amdgcn_mfma_f32_16x16x32_bf16(a[mt], b[nt], acc[mt][nt], 0, 0, 0);
    }

#pragma unroll
    for (int mt = 0; mt < 4; mt++) {
        const int mb = m0 + wr*64 + mt*16 + quad*4;
#pragma unroll
        for (int nt = 0; nt < 4; nt++) {
            const int n = n0 + wc*64 + nt*16 + l15;
            const float bias = bo[n];
#pragma unroll
            for (int r = 0; r < 4; r++)
                out[(mb + r)*1024 + n] = acc[mt][nt][r] + bias;
        }
    }
}

// ---------------------------------------------------------------------------
// FALLBACK GEMMs (fp32 inputs, cvt fused in staging)
// ---------------------------------------------------------------------------
__global__ __launch_bounds__(256)
void gemm_qkv(const float* __restrict__ x, const float* __restrict__ Wq,
              const float* __restrict__ Wk, const float* __restrict__ Wv,
              bf16* __restrict__ qd, bf16* __restrict__ kd, bf16* __restrict__ vtd)
{
    const int mode = blockIdx.z;
    const float* __restrict__ W = (mode == 0) ? Wq : (mode == 1) ? Wk : Wv;
    const int m0 = blockIdx.x * 128;
    const int n0 = blockIdx.y * 128;
    __shared__ bf16 As[128 * 40];
    __shared__ bf16 Bs[128 * 40];
    const int t    = threadIdx.x;
    const int lane = t & 63, w = t >> 6;
    const int wr = w >> 1, wc = w & 1;
    const int l15 = lane & 15, quad = lane >> 4;
    const int srow = t >> 2, scol = (t & 3) * 8;
    v4f acc[4][4] = {};

    for (int k0 = 0; k0 < 1024; k0 += 32) {
        __syncthreads();
        {
            const float* pa = &x[(m0 + srow) * 1024 + k0 + scol];
            *(v8s*)&As[srow*40 + scol] = pack_bf16x8(*(const float4*)pa, *(const float4*)(pa + 4));
            const float* pa2 = pa + 64 * 1024;
            *(v8s*)&As[(srow+64)*40 + scol] = pack_bf16x8(*(const float4*)pa2, *(const float4*)(pa2 + 4));
            const float* pb = &W[(n0 + srow) * 1024 + k0 + scol];
            *(v8s*)&Bs[srow*40 + scol] = pack_bf16x8(*(const float4*)pb, *(const float4*)(pb + 4));
            const float* pb2 = pb + 64 * 1024;
            *(v8s*)&Bs[(srow+64)*40 + scol] = pack_bf16x8(*(const float4*)pb2, *(const float4*)(pb2 + 4));
        }
        __syncthreads();
        v8s a[4], b[4];
#pragma unroll
        for (int mt = 0; mt < 4; mt++) a[mt] = *(const v8s*)&As[(wr*64 + mt*16 + l15)*40 + quad*8];
#pragma unroll
        for (int nt = 0; nt < 4; nt++) b[nt] = *(const v8s*)&Bs[(wc*64 + nt*16 + l15)*40 + quad*8];
#pragma unroll
        for (int mt = 0; mt < 4; mt++)
#pragma unroll
            for (int nt = 0; nt < 4; nt++)
                acc[mt][nt] = __builtin_amdgcn_mfma_f32_16x16x32_bf16(a[mt], b[nt], acc[mt][nt], 0, 0, 0);
    }

    const float qscale = (mode == 0) ? C2 : 1.0f;
#pragma unroll
    for (int mt = 0; mt < 4; mt++) {
        const int mb = m0 + wr*64 + mt*16 + quad*4;
        const int b_ = mb >> 11, s = mb & 2047;
#pragma unroll
        for (int nt = 0; nt < 4; nt++) {
            const int n = n0 + wc*64 + nt*16 + l15;
            const int h = n >> 6, d = n & 63;
            if (mode == 2) {
                unsigned int lo = (unsigned int)bf16_bits(__float2bfloat16(acc[mt][nt][0]))
                                | ((unsigned int)bf16_bits(__float2bfloat16(acc[mt][nt][1])) << 16);
                unsigned int hi = (unsigned int)bf16_bits(__float2bfloat16(acc[mt][nt][2]))
                                | ((unsigned int)bf16_bits(__float2bfloat16(acc[mt][nt][3])) << 16);
                uint2 pv; pv.x = lo; pv.y = hi;
                *(uint2*)&vtd[((b_*H_ + h)*HD_ + d)*S_ + s] = pv;
            } else {
                bf16* __restrict__ dst = (mode == 0) ? qd : kd;
#pragma unroll
                for (int r = 0; r < 4; r++)
                    dst[((b_*H_ + h)*S_ + (s + r))*HD_ + d] = __float2bfloat16(acc[mt][nt][r] * qscale);
            }
        }
    }
}

__global__ __launch_bounds__(256)
void gemm_out(const bf16* __restrict__ ctx, const float* __restrict__ Wo,
              const float* __restrict__ bo, float* __restrict__ out)
{
    const int m0 = blockIdx.x * 128;
    const int n0 = blockIdx.y * 128;
    __shared__ bf16 As[128 * 40];
    __shared__ bf16 Bs[128 * 40];
    const int t    = threadIdx.x;
    const int lane = t & 63, w = t >> 6;
    const int wr = w >> 1, wc = w & 1;
    const int l15 = lane & 15, quad = lane >> 4;
    const int srow = t >> 2, scol = (t & 3) * 8;
    v4f acc[4][4] = {};

    for (int k0 = 0; k0 < 1024; k0 += 32) {
        __syncthreads();
        {
            *(v8s*)&As[srow*40 + scol]      = *(const v8s*)&ctx[(m0+srow)*1024 + k0 + scol];
            *(v8s*)&As[(srow+64)*40 + scol] = *(const v8s*)&ctx[(m0+srow+64)*1024 + k0 + scol];
            const float* pb = &Wo[(n0 + srow) * 1024 + k0 + scol];
            *(v8s*)&Bs[srow*40 + scol] = pack_bf16x8(*(const float4*)pb, *(const float4*)(pb + 4));
            const float* pb2 = pb + 64 * 1024;
            *(v8s*)&Bs[(srow+64)*40 + scol] = pack_bf16x8(*(const float4*)pb2, *(const float4*)(pb2 + 4));
        }
        __syncthreads();
        v8s a[4], b[4];
#pragma unroll
        for (int mt = 0; mt < 4; mt++) a[mt] = *(const v8s*)&As[(wr*64 + mt*16 + l15)*40 + quad*8];
#pragma unroll
        for (int nt = 0; nt < 4; nt++) b[nt] = *(const v8s*)&Bs[(wc*64 + nt*16 + l15)*40 + quad*8];
#pragma unroll
        for (int mt = 0; mt < 4; mt++)
#pragma unroll
            for (int nt = 0; nt < 4; nt++)
                acc[mt][nt] = __builtin_amdgcn_mfma_f32_16x16x32_bf16(a[mt], b[nt], acc[mt][nt], 0, 0, 0);
    }

#pragma unroll
    for (int mt = 0; mt < 4; mt++) {
        const int mb = m0 + wr*64 + mt*16 + quad*4;
#pragma unroll
        for (int nt = 0; nt < 4; nt++) {
            const int n = n0 + wc*64 + nt*16 + l15;
            const float bias = bo[n];
#pragma unroll
            for (int r = 0; r < 4; r++)
                out[(mb + r)*1024 + n] = acc[mt][nt][r] + bias;
        }
    }
}

// ---------------------------------------------------------------------------
// Causal flash attention v5: single barrier per tile with NOTHING outstanding
// at the barrier (prefetch issued AFTER it, consumed next iter) -> no vmcnt
// drain; prefetch latency hidden behind a full compute phase. Fixed-offset
// exp2 softmax (linear -> split-K partials add).
// ---------------------------------------------------------------------------
__global__ __launch_bounds__(256)
void flash_attn(const bf16* __restrict__ qd, const bf16* __restrict__ kd,
                const bf16* __restrict__ vtd, bf16* __restrict__ outp,
                float* __restrict__ lsum)
{
    const int qb = 15 - blockIdx.x;
    const int bh = blockIdx.y;
    const int split = blockIdx.z;
    const bool dosplit = (gridDim.z == 2);
    const int t = threadIdx.x;
    const int lane = t & 63, w = t >> 6;
    const int l15 = lane & 15, quad = lane >> 4;
    const int q0 = qb * 128;

    const int tbeg = dosplit ? split * (qb + 1) : 0;
    const int tend = dosplit ? tbeg + qb + 1 : 2 * qb + 2;

    __shared__ bf16 Ks[2][64 * 72];
    __shared__ bf16 Vs[2][64 * 72];
    __shared__ bf16 Pl[4][16 * 72];

    const int mrow0 = q0 + w * 16;
    const int mrow1 = q0 + 64 + w * 16;

    v8s qf[2][2];
#pragma unroll
    for (int mt = 0; mt < 2; mt++) {
        const bf16* qb_ = qd + (bh*S_ + (mt ? mrow1 : mrow0) + l15) * HD_;
        qf[mt][0] = *(const v8s*)(qb_ + quad*8);
        qf[mt][1] = *(const v8s*)(qb_ + 32 + quad*8);
    }

    v4f o[2][4] = {};
    float ps[2][4] = {};

    const int rowlo = t >> 3, col8 = (t & 7) * 8;

    int c0 = tbeg * 64;
    v8s pk0 = *(const v8s*)&kd[(bh*S_ + c0 + rowlo)*HD_ + col8];
    v8s pk1 = *(const v8s*)&kd[(bh*S_ + c0 + rowlo + 32)*HD_ + col8];
    v8s pv0 = *(const v8s*)&vtd[(bh*HD_ + rowlo)*S_ + c0 + col8];
    v8s pv1 = *(const v8s*)&vtd[(bh*HD_ + rowlo + 32)*S_ + c0 + col8];

    for (int it = tbeg; it < tend; ++it) {
        c0 = it * 64;
        bf16* Kb = &Ks[it & 1][0];
        bf16* Vb = &Vs[it & 1][0];
        // stage current tile (regs loaded during previous iteration's compute)
        *(v8s*)&Kb[rowlo*72 + col8]      = pk0;
        *(v8s*)&Kb[(rowlo+32)*72 + col8] = pk1;
        *(v8s*)&Vb[rowlo*72 + col8]      = pv0;
        *(v8s*)&Vb[(rowlo+32)*72 + col8] = pv1;
        __syncthreads();                  // nothing outstanding: no vmcnt drain
        // prefetch NEXT tile now — a full compute phase to land
        const int cn = (it + 1 < tend) ? c0 + 64 : tbeg * 64;
        pk0 = *(const v8s*)&kd[(bh*S_ + cn + rowlo)*HD_ + col8];
        pk1 = *(const v8s*)&kd[(bh*S_ + cn + rowlo + 32)*HD_ + col8];
        pv0 = *(const v8s*)&vtd[(bh*HD_ + rowlo)*S_ + cn + col8];
        pv1 = *(const v8s*)&vtd[(bh*HD_ + rowlo + 32)*S_ + cn + col8];

        if (c0 <= mrow1 + 15) {
            v8s kf[4][2];
#pragma unroll
            for (int kt = 0; kt < 4; kt++) {
                kf[kt][0] = *(const v8s*)&Kb[(kt*16 + l15)*72 + quad*8];
                kf[kt][1] = *(const v8s*)&Kb[(kt*16 + l15)*72 + 32 + quad*8];
            }
            v8s vf[4][2];
#pragma unroll
            for (int dt = 0; dt < 4; dt++) {
                vf[dt][0] = *(const v8s*)&Vb[(dt*16 + l15)*72 + quad*8];
                vf[dt][1] = *(const v8s*)&Vb[(dt*16 + l15)*72 + 32 + quad*8];
            }

#pragma unroll
            for (int mt = 0; mt < 2; mt++) {
                const int mr = mt ? mrow1 : mrow0;
                if (c0 > mr + 15) continue;
                v4f sc[4] = {};
#pragma unroll
                for (int kt = 0; kt < 4; kt++) {
                    sc[kt] = __builtin_amdgcn_mfma_f32_16x16x32_bf16(qf[mt][0], kf[kt][0], sc[kt], 0, 0, 0);
                    sc[kt] = __builtin_amdgcn_mfma_f32_16x16x32_bf16(qf[mt][1], kf[kt][1], sc[kt], 0, 0, 0);
                }
                const bool full = (c0 + 63 <= mr);
#pragma unroll
                for (int r = 0; r < 4; r++) {
                    const int qg = mr + quad*4 + r;
#pragma unroll
                    for (int kt = 0; kt < 4; kt++) {
                        float s = sc[kt][r];
                        if (!full) {
                            const int kg = c0 + kt*16 + l15;
                            s = (kg <= qg) ? s : NEG_BIG;
                        }
                        const float p = EXP2F(s);
                        sc[kt][r] = p;
                        ps[mt][r] += p;
                    }
                }
                bf16* pw = &Pl[w][0];
#pragma unroll
                for (int kt = 0; kt < 4; kt++)
#pragma unroll
                    for (int r = 0; r < 4; r++)
                        pw[(quad*4 + r)*72 + kt*16 + l15] = __float2bfloat16(sc[kt][r]);
                v8s pf0 = *(const v8s*)&pw[l15*72 + quad*8];
                v8s pf1 = *(const v8s*)&pw[l15*72 + 32 + quad*8];
#pragma unroll
                for (int dt = 0; dt < 4; dt++) {
                    o[mt][dt] = __builtin_amdgcn_mfma_f32_16x16x32_bf16(pf0, vf[dt][0], o[mt][dt], 0, 0, 0);
                    o[mt][dt] = __builtin_amdgcn_mfma_f32_16x16x32_bf16(pf1, vf[dt][1], o[mt][dt], 0, 0, 0);
                }
            }
        }
    }

    const int b_ = bh >> 4, h = bh & 15;
    bf16* __restrict__ po = outp + (size_t)split * (4 * 1024 * 1024);
    float* __restrict__ ls = lsum + split * (32 * S_);
#pragma unroll
    for (int mt = 0; mt < 2; mt++) {
        const int mr = mt ? mrow1 : mrow0;
#pragma unroll
        for (int r = 0; r < 4; r++) {
            float l = ps[mt][r];
#pragma unroll
            for (int off = 1; off < 16; off <<= 1) l += __shfl_xor(l, off);
            const int qg = mr + quad*4 + r;
            if (!dosplit) {
                const float linv = 1.0f / l;
#pragma unroll
                for (int dt = 0; dt < 4; dt++)
                    outp[(b_*S_ + qg)*D_ + h*HD_ + dt*16 + l15] = __float2bfloat16(o[mt][dt][r] * linv);
            } else {
                if (l15 == 0) ls[bh*S_ + qg] = l;
#pragma unroll
                for (int dt = 0; dt < 4; dt++)
                    po[(b_*S_ + qg)*D_ + h*HD_ + dt*16 + l15] = __float2bfloat16(o[mt][dt][r]);
            }
        }
    }
}

// ---------------------------------------------------------------------------
// split-K combine: ctx = (O0 + O1) / (l0 + l1)
// ---------------------------------------------------------------------------
__global__ __launch_bounds__(256)
void combine_k(const bf16* __restrict__ po, const float* __restrict__ lsum,
               bf16* __restrict__ ctx)
{
    const int idx = (blockIdx.x * 256 + threadIdx.x) * 8;
    const int row = idx >> 10;
    const int h = (idx & 1023) >> 6;
    const int b = row >> 11, s = row & 2047;
    const int bh = b * 16 + h;
    const float linv = 1.0f / (lsum[bh*S_ + s] + lsum[32*S_ + bh*S_ + s]);
    union { v8s v; unsigned short u[8]; } a, c, r;
    a.v = *(const v8s*)&po[idx];
    c.v = *(const v8s*)&po[4*1024*1024 + idx];
#pragma unroll
    for (int j = 0; j < 8; j++)
        r.u[j] = bf16_bits(__float2bfloat16((bits2f(a.u[j]) + bits2f(c.u[j])) * linv));
    *(v8s*)&ctx[idx] = r.v;
}

extern "C" void kernel_launch(void* const* d_in, const int* in_sizes, int n_in,
                              void* d_out, int out_size, void* d_ws, size_t ws_size,
                              hipStream_t stream) {
    const float* x  = (const float*)d_in[0];
    const float* Wq = (const float*)d_in[1];
    const float* Wk = (const float*)d_in[2];
    const float* Wv = (const float*)d_in[3];
    const float* Wo = (const float*)d_in[4];
    const float* bo = (const float*)d_in[5];
    float* out = (float*)d_out;

    const size_t SEG = (size_t)2 * H_ * S_ * HD_;      // 4 Mi bf16 elems = 8 MB
    bf16* qd  = (bf16*)d_ws;
    bf16* kd  = qd  + SEG;
    bf16* vtd = kd  + SEG;
    bf16* xc  = vtd + SEG;                             // x-bf16, later ctx
    bf16* wqb = xc + SEG;
    bf16* wkb = wqb + 1024 * 1024;
    bf16* wvb = wkb + 1024 * 1024;
    bf16* wob = wvb + 1024 * 1024;
    bf16* po  = wob + 1024 * 1024;                     // 2 x 4 Mi elems
    float* lsum = (float*)(po + 2 * SEG);

    const size_t need_fast  = (4 * SEG + 4 * 1024 * 1024) * sizeof(bf16);
    const size_t need_split = need_fast + 2 * SEG * sizeof(bf16) + 2 * 32 * S_ * sizeof(float);

    if (ws_size >= need_split) {
        cvt_bf16<<<dim3(2048, 5), 256, 0, stream>>>(x, Wq, Wk, Wv, Wo,
                                                    xc, wqb, wkb, wvb, wob);
        gemm_qkv_f<<<dim3(32, 8, 3), 256, 0, stream>>>(xc, wqb, wkb, wvb, qd, kd, vtd);
        flash_attn<<<dim3(16, 32, 2), 256, 0, stream>>>(qd, kd, vtd, po, lsum);
        combine_k<<<dim3(2048), 256, 0, stream>>>(po, lsum, xc);
        gemm_out_f<<<dim3(32, 8), 256, 0, stream>>>(xc, wob, bo, out);
    } else if (ws_size >= need_fast) {
        cvt_bf16<<<dim3(2048, 5), 256, 0, stream>>>(x, Wq, Wk, Wv, Wo,
                                                    xc, wqb, wkb, wvb, wob);
        gemm_qkv_f<<<dim3(32, 8, 3), 256, 0, stream>>>(xc, wqb, wkb, wvb, qd, kd, vtd);
        flash_attn<<<dim3(16, 32, 1), 256, 0, stream>>>(qd, kd, vtd, xc, lsum);
        gemm_out_f<<<dim3(32, 8), 256, 0, stream>>>(xc, wob, bo, out);
    } else {
        gemm_qkv<<<dim3(32, 8, 3), 256, 0, stream>>>(x, Wq, Wk, Wv, qd, kd, vtd);
        flash_attn<<<dim3(16, 32, 1), 256, 0, stream>>>(qd, kd, vtd, xc, (float*)xc);
        gemm_out<<<dim3(32, 8), 256, 0, stream>>>(xc, Wo, bo, out);
    }
}

// Round 11
// 210.521 us; speedup vs baseline: 1.0953x; 1.0938x over previous
//
#include <hip/hip_runtime.h>
#include <hip/hip_bf16.h>

typedef __hip_bfloat16 bf16;
typedef short v8s __attribute__((ext_vector_type(8)));
typedef float v4f __attribute__((ext_vector_type(4)));

#define S_ 2048
#define D_ 1024
#define H_ 16
#define HD_ 64

#define EXP2F(x) __builtin_amdgcn_exp2f(x)   /* v_exp_f32: 2^x on gfx950 */
#define NEG_BIG (-1.0e30f)
#define C2 0.1803368801111244f   /* (1/sqrt(64)) * log2(e), folded into Q */

#define GLDS16(g, l) __builtin_amdgcn_global_load_lds(                        \
    (const __attribute__((address_space(1))) unsigned int*)(g),               \
    (__attribute__((address_space(3))) unsigned int*)(l), 16, 0, 0)

static __device__ __forceinline__ unsigned short bf16_bits(bf16 h) {
    union { bf16 h; unsigned short u; } c; c.h = h; return c.u;
}

static __device__ __forceinline__ v8s pack_bf16x8(const float4 a, const float4 b) {
    union { v8s v; unsigned short u[8]; } r;
    r.u[0] = bf16_bits(__float2bfloat16(a.x));
    r.u[1] = bf16_bits(__float2bfloat16(a.y));
    r.u[2] = bf16_bits(__float2bfloat16(a.z));
    r.u[3] = bf16_bits(__float2bfloat16(a.w));
    r.u[4] = bf16_bits(__float2bfloat16(b.x));
    r.u[5] = bf16_bits(__float2bfloat16(b.y));
    r.u[6] = bf16_bits(__float2bfloat16(b.z));
    r.u[7] = bf16_bits(__float2bfloat16(b.w));
    return r.v;
}

// ---------------------------------------------------------------------------
// fp32 -> bf16 conversion pre-pass
// ---------------------------------------------------------------------------
__global__ __launch_bounds__(256)
void cvt_bf16(const float* __restrict__ x,  const float* __restrict__ wq,
              const float* __restrict__ wk, const float* __restrict__ wv,
              const float* __restrict__ wo,
              bf16* __restrict__ xb,  bf16* __restrict__ wqb,
              bf16* __restrict__ wkb, bf16* __restrict__ wvb,
              bf16* __restrict__ wob)
{
    const int seg = blockIdx.y;
    const float* src; bf16* dst; int n;
    switch (seg) {
        case 0: src = x;  dst = xb;  n = 4096 * 1024; break;
        case 1: src = wq; dst = wqb; n = 1024 * 1024; break;
        case 2: src = wk; dst = wkb; n = 1024 * 1024; break;
        case 3: src = wv; dst = wvb; n = 1024 * 1024; break;
        default:src = wo; dst = wob; n = 1024 * 1024; break;
    }
    const int idx = (blockIdx.x * 256 + threadIdx.x) * 8;
    if (idx >= n) return;
    *(v8s*)&dst[idx] = pack_bf16x8(*(const float4*)&src[idx],
                                   *(const float4*)&src[idx + 4]);
}

// ---------------------------------------------------------------------------
// FAST NT GEMM (m97-style): bf16 inputs, global_load_lds width-16 staging.
// ---------------------------------------------------------------------------
__global__ __launch_bounds__(256)
void gemm_qkv_f(const bf16* __restrict__ xb, const bf16* __restrict__ wqb,
                const bf16* __restrict__ wkb, const bf16* __restrict__ wvb,
                bf16* __restrict__ qd, bf16* __restrict__ kd, bf16* __restrict__ vtd)
{
    const int mode = blockIdx.z;
    const bf16* __restrict__ W = (mode == 0) ? wqb : (mode == 1) ? wkb : wvb;
    const int m0 = blockIdx.x * 128;
    const int n0 = blockIdx.y * 128;
    __shared__ bf16 As[128 * 32];
    __shared__ bf16 Bs[128 * 32];
    const int t    = threadIdx.x;
    const int lane = t & 63, w = t >> 6;
    const int wr = w >> 1, wc = w & 1;
    const int l15 = lane & 15, quad = lane >> 4;
    const int r16 = lane >> 2, c8 = (lane & 3) * 8;
    v4f acc[4][4] = {};

    const bf16* ga = &xb[(m0 + w*16 + r16) * 1024 + c8];
    const bf16* gb = &W [(n0 + w*16 + r16) * 1024 + c8];
    bf16* la0 = &As[w * 16 * 32];
    bf16* la1 = &As[(64 + w * 16) * 32];
    bf16* lb0 = &Bs[w * 16 * 32];
    bf16* lb1 = &Bs[(64 + w * 16) * 32];

    for (int k0 = 0; k0 < 1024; k0 += 32) {
        __syncthreads();
        GLDS16(ga + k0,             la0);
        GLDS16(ga + k0 + 64 * 1024, la1);
        GLDS16(gb + k0,             lb0);
        GLDS16(gb + k0 + 64 * 1024, lb1);
        __syncthreads();
        v8s a[4], b[4];
#pragma unroll
        for (int mt = 0; mt < 4; mt++) a[mt] = *(const v8s*)&As[(wr*64 + mt*16 + l15)*32 + quad*8];
#pragma unroll
        for (int nt = 0; nt < 4; nt++) b[nt] = *(const v8s*)&Bs[(wc*64 + nt*16 + l15)*32 + quad*8];
#pragma unroll
        for (int mt = 0; mt < 4; mt++)
#pragma unroll
            for (int nt = 0; nt < 4; nt++)
                acc[mt][nt] = __builtin_amdgcn_mfma_f32_16x16x32_bf16(a[mt], b[nt], acc[mt][nt], 0, 0, 0);
    }

    const float qscale = (mode == 0) ? C2 : 1.0f;
#pragma unroll
    for (int mt = 0; mt < 4; mt++) {
        const int mb = m0 + wr*64 + mt*16 + quad*4;
        const int b_ = mb >> 11, s = mb & 2047;
#pragma unroll
        for (int nt = 0; nt < 4; nt++) {
            const int n = n0 + wc*64 + nt*16 + l15;
            const int h = n >> 6, d = n & 63;
            if (mode == 2) {
                unsigned int lo = (unsigned int)bf16_bits(__float2bfloat16(acc[mt][nt][0]))
                                | ((unsigned int)bf16_bits(__float2bfloat16(acc[mt][nt][1])) << 16);
                unsigned int hi = (unsigned int)bf16_bits(__float2bfloat16(acc[mt][nt][2]))
                                | ((unsigned int)bf16_bits(__float2bfloat16(acc[mt][nt][3])) << 16);
                uint2 pv; pv.x = lo; pv.y = hi;
                *(uint2*)&vtd[((b_*H_ + h)*HD_ + d)*S_ + s] = pv;
            } else {
                bf16* __restrict__ dst = (mode == 0) ? qd : kd;
#pragma unroll
                for (int r = 0; r < 4; r++)
                    dst[((b_*H_ + h)*S_ + (s + r))*HD_ + d] = __float2bfloat16(acc[mt][nt][r] * qscale);
            }
        }
    }
}

__global__ __launch_bounds__(256)
void gemm_out_f(const bf16* __restrict__ ctx, const bf16* __restrict__ wob,
                const float* __restrict__ bo, float* __restrict__ out)
{
    const int m0 = blockIdx.x * 128;
    const int n0 = blockIdx.y * 128;
    __shared__ bf16 As[128 * 32];
    __shared__ bf16 Bs[128 * 32];
    const int t    = threadIdx.x;
    const int lane = t & 63, w = t >> 6;
    const int wr = w >> 1, wc = w & 1;
    const int l15 = lane & 15, quad = lane >> 4;
    const int r16 = lane >> 2, c8 = (lane & 3) * 8;
    v4f acc[4][4] = {};

    const bf16* ga = &ctx[(m0 + w*16 + r16) * 1024 + c8];
    const bf16* gb = &wob[(n0 + w*16 + r16) * 1024 + c8];
    bf16* la0 = &As[w * 16 * 32];
    bf16* la1 = &As[(64 + w * 16) * 32];
    bf16* lb0 = &Bs[w * 16 * 32];
    bf16* lb1 = &Bs[(64 + w * 16) * 32];

    for (int k0 = 0; k0 < 1024; k0 += 32) {
        __syncthreads();
        GLDS16(ga + k0,             la0);
        GLDS16(ga + k0 + 64 * 1024, la1);
        GLDS16(gb + k0,             lb0);
        GLDS16(gb + k0 + 64 * 1024, lb1);
        __syncthreads();
        v8s a[4], b[4];
#pragma unroll
        for (int mt = 0; mt < 4; mt++) a[mt] = *(const v8s*)&As[(wr*64 + mt*16 + l15)*32 + quad*8];
#pragma unroll
        for (int nt = 0; nt < 4; nt++) b[nt] = *(const v8s*)&Bs[(wc*64 + nt*16 + l15)*32 + quad*8];
#pragma unroll
        for (int mt = 0; mt < 4; mt++)
#pragma unroll
            for (int nt = 0; nt < 4; nt++)
                acc[mt][nt] = __builtin_amdgcn_mfma_f32_16x16x32_bf16(a[mt], b[nt], acc[mt][nt], 0, 0, 0);
    }

#pragma unroll
    for (int mt = 0; mt < 4; mt++) {
        const int mb = m0 + wr*64 + mt*16 + quad*4;
#pragma unroll
        for (int nt = 0; nt < 4; nt++) {
            const int n = n0 + wc*64 + nt*16 + l15;
            const float bias = bo[n];
#pragma unroll
            for (int r = 0; r < 4; r++)
                out[(mb + r)*1024 + n] = acc[mt][nt][r] + bias;
        }
    }
}

// ---------------------------------------------------------------------------
// FALLBACK GEMMs (fp32 inputs, cvt fused in staging)
// ---------------------------------------------------------------------------
__global__ __launch_bounds__(256)
void gemm_qkv(const float* __restrict__ x, const float* __restrict__ Wq,
              const float* __restrict__ Wk, const float* __restrict__ Wv,
              bf16* __restrict__ qd, bf16* __restrict__ kd, bf16* __restrict__ vtd)
{
    const int mode = blockIdx.z;
    const float* __restrict__ W = (mode == 0) ? Wq : (mode == 1) ? Wk : Wv;
    const int m0 = blockIdx.x * 128;
    const int n0 = blockIdx.y * 128;
    __shared__ bf16 As[128 * 40];
    __shared__ bf16 Bs[128 * 40];
    const int t    = threadIdx.x;
    const int lane = t & 63, w = t >> 6;
    const int wr = w >> 1, wc = w & 1;
    const int l15 = lane & 15, quad = lane >> 4;
    const int srow = t >> 2, scol = (t & 3) * 8;
    v4f acc[4][4] = {};

    for (int k0 = 0; k0 < 1024; k0 += 32) {
        __syncthreads();
        {
            const float* pa = &x[(m0 + srow) * 1024 + k0 + scol];
            *(v8s*)&As[srow*40 + scol] = pack_bf16x8(*(const float4*)pa, *(const float4*)(pa + 4));
            const float* pa2 = pa + 64 * 1024;
            *(v8s*)&As[(srow+64)*40 + scol] = pack_bf16x8(*(const float4*)pa2, *(const float4*)(pa2 + 4));
            const float* pb = &W[(n0 + srow) * 1024 + k0 + scol];
            *(v8s*)&Bs[srow*40 + scol] = pack_bf16x8(*(const float4*)pb, *(const float4*)(pb + 4));
            const float* pb2 = pb + 64 * 1024;
            *(v8s*)&Bs[(srow+64)*40 + scol] = pack_bf16x8(*(const float4*)pb2, *(const float4*)(pb2 + 4));
        }
        __syncthreads();
        v8s a[4], b[4];
#pragma unroll
        for (int mt = 0; mt < 4; mt++) a[mt] = *(const v8s*)&As[(wr*64 + mt*16 + l15)*40 + quad*8];
#pragma unroll
        for (int nt = 0; nt < 4; nt++) b[nt] = *(const v8s*)&Bs[(wc*64 + nt*16 + l15)*40 + quad*8];
#pragma unroll
        for (int mt = 0; mt < 4; mt++)
#pragma unroll
            for (int nt = 0; nt < 4; nt++)
                acc[mt][nt] = __builtin_amdgcn_mfma_f32_16x16x32_bf16(a[mt], b[nt], acc[mt][nt], 0, 0, 0);
    }

    const float qscale = (mode == 0) ? C2 : 1.0f;
#pragma unroll
    for (int mt = 0; mt < 4; mt++) {
        const int mb = m0 + wr*64 + mt*16 + quad*4;
        const int b_ = mb >> 11, s = mb & 2047;
#pragma unroll
        for (int nt = 0; nt < 4; nt++) {
            const int n = n0 + wc*64 + nt*16 + l15;
            const int h = n >> 6, d = n & 63;
            if (mode == 2) {
                unsigned int lo = (unsigned int)bf16_bits(__float2bfloat16(acc[mt][nt][0]))
                                | ((unsigned int)bf16_bits(__float2bfloat16(acc[mt][nt][1])) << 16);
                unsigned int hi = (unsigned int)bf16_bits(__float2bfloat16(acc[mt][nt][2]))
                                | ((unsigned int)bf16_bits(__float2bfloat16(acc[mt][nt][3])) << 16);
                uint2 pv; pv.x = lo; pv.y = hi;
                *(uint2*)&vtd[((b_*H_ + h)*HD_ + d)*S_ + s] = pv;
            } else {
                bf16* __restrict__ dst = (mode == 0) ? qd : kd;
#pragma unroll
                for (int r = 0; r < 4; r++)
                    dst[((b_*H_ + h)*S_ + (s + r))*HD_ + d] = __float2bfloat16(acc[mt][nt][r] * qscale);
            }
        }
    }
}

__global__ __launch_bounds__(256)
void gemm_out(const bf16* __restrict__ ctx, const float* __restrict__ Wo,
              const float* __restrict__ bo, float* __restrict__ out)
{
    const int m0 = blockIdx.x * 128;
    const int n0 = blockIdx.y * 128;
    __shared__ bf16 As[128 * 40];
    __shared__ bf16 Bs[128 * 40];
    const int t    = threadIdx.x;
    const int lane = t & 63, w = t >> 6;
    const int wr = w >> 1, wc = w & 1;
    const int l15 = lane & 15, quad = lane >> 4;
    const int srow = t >> 2, scol = (t & 3) * 8;
    v4f acc[4][4] = {};

    for (int k0 = 0; k0 < 1024; k0 += 32) {
        __syncthreads();
        {
            *(v8s*)&As[srow*40 + scol]      = *(const v8s*)&ctx[(m0+srow)*1024 + k0 + scol];
            *(v8s*)&As[(srow+64)*40 + scol] = *(const v8s*)&ctx[(m0+srow+64)*1024 + k0 + scol];
            const float* pb = &Wo[(n0 + srow) * 1024 + k0 + scol];
            *(v8s*)&Bs[srow*40 + scol] = pack_bf16x8(*(const float4*)pb, *(const float4*)(pb + 4));
            const float* pb2 = pb + 64 * 1024;
            *(v8s*)&Bs[(srow+64)*40 + scol] = pack_bf16x8(*(const float4*)pb2, *(const float4*)(pb2 + 4));
        }
        __syncthreads();
        v8s a[4], b[4];
#pragma unroll
        for (int mt = 0; mt < 4; mt++) a[mt] = *(const v8s*)&As[(wr*64 + mt*16 + l15)*40 + quad*8];
#pragma unroll
        for (int nt = 0; nt < 4; nt++) b[nt] = *(const v8s*)&Bs[(wc*64 + nt*16 + l15)*40 + quad*8];
#pragma unroll
        for (int mt = 0; mt < 4; mt++)
#pragma unroll
            for (int nt = 0; nt < 4; nt++)
                acc[mt][nt] = __builtin_amdgcn_mfma_f32_16x16x32_bf16(a[mt], b[nt], acc[mt][nt], 0, 0, 0);
    }

#pragma unroll
    for (int mt = 0; mt < 4; mt++) {
        const int mb = m0 + wr*64 + mt*16 + quad*4;
#pragma unroll
        for (int nt = 0; nt < 4; nt++) {
            const int n = n0 + wc*64 + nt*16 + l15;
            const float bias = bo[n];
#pragma unroll
            for (int r = 0; r < 4; r++)
                out[(mb + r)*1024 + n] = acc[mt][nt][r] + bias;
        }
    }
}

// ---------------------------------------------------------------------------
// Causal flash attention v6: grid x=bh (XCD co-location: all q-blocks of one
// head land on one XCD -> K/V stays in that XCD's 4MB L2), y -> qb reversed.
// Single barrier/tile, reg-prefetch double buffer, fixed-offset exp2 softmax,
// pointer-increment addressing. Prefetch overrun (<=4KB past segment) stays
// inside the workspace.
// ---------------------------------------------------------------------------
__global__ __launch_bounds__(256)
void flash_attn(const bf16* __restrict__ qd, const bf16* __restrict__ kd,
                const bf16* __restrict__ vtd, bf16* __restrict__ ctx)
{
    const int bh = blockIdx.x;            // 0..31 — same bh => same XCD
    const int qb = 15 - blockIdx.y;       // reversed: longest blocks first
    const int t = threadIdx.x;
    const int lane = t & 63, w = t >> 6;
    const int l15 = lane & 15, quad = lane >> 4;
    const int q0 = qb * 128;
    const int nT = 2 * qb + 2;

    __shared__ bf16 Ks[2][64 * 72];
    __shared__ bf16 Vs[2][64 * 72];
    __shared__ bf16 Pl[4][16 * 72];

    const int mrow0 = q0 + w * 16;
    const int mrow1 = q0 + 64 + w * 16;

    v8s qf[2][2];
#pragma unroll
    for (int mt = 0; mt < 2; mt++) {
        const bf16* qb_ = qd + (bh*S_ + (mt ? mrow1 : mrow0) + l15) * HD_;
        qf[mt][0] = *(const v8s*)(qb_ + quad*8);
        qf[mt][1] = *(const v8s*)(qb_ + 32 + quad*8);
    }

    v4f o[2][4] = {};
    float ps[2][4] = {};

    const int rowlo = t >> 3, col8 = (t & 7) * 8;
    // streaming pointers (advance per tile; unclamped prefetch stays in ws)
    const bf16* kp = kd  + (bh*S_ + rowlo)*HD_ + col8;
    const bf16* vp = vtd + (bh*HD_ + rowlo)*S_ + col8;

    v8s pk0 = *(const v8s*)(kp);
    v8s pk1 = *(const v8s*)(kp + 32*HD_);
    v8s pv0 = *(const v8s*)(vp);
    v8s pv1 = *(const v8s*)(vp + 32*S_);

    for (int it = 0; it < nT; ++it) {
        const int c0 = it * 64;
        bf16* Kb = &Ks[it & 1][0];
        bf16* Vb = &Vs[it & 1][0];
        *(v8s*)&Kb[rowlo*72 + col8]      = pk0;
        *(v8s*)&Kb[(rowlo+32)*72 + col8] = pk1;
        *(v8s*)&Vb[rowlo*72 + col8]      = pv0;
        *(v8s*)&Vb[(rowlo+32)*72 + col8] = pv1;
        __syncthreads();                  // nothing outstanding at the barrier
        kp += 64 * HD_;
        vp += 64;
        pk0 = *(const v8s*)(kp);
        pk1 = *(const v8s*)(kp + 32*HD_);
        pv0 = *(const v8s*)(vp);
        pv1 = *(const v8s*)(vp + 32*S_);

        if (c0 <= mrow1 + 15) {
            v8s kf[4][2];
#pragma unroll
            for (int kt = 0; kt < 4; kt++) {
                kf[kt][0] = *(const v8s*)&Kb[(kt*16 + l15)*72 + quad*8];
                kf[kt][1] = *(const v8s*)&Kb[(kt*16 + l15)*72 + 32 + quad*8];
            }
            v8s vf[4][2];
#pragma unroll
            for (int dt = 0; dt < 4; dt++) {
                vf[dt][0] = *(const v8s*)&Vb[(dt*16 + l15)*72 + quad*8];
                vf[dt][1] = *(const v8s*)&Vb[(dt*16 + l15)*72 + 32 + quad*8];
            }

#pragma unroll
            for (int mt = 0; mt < 2; mt++) {
                const int mr = mt ? mrow1 : mrow0;
                if (c0 > mr + 15) continue;
                v4f sc[4] = {};
#pragma unroll
                for (int kt = 0; kt < 4; kt++) {
                    sc[kt] = __builtin_amdgcn_mfma_f32_16x16x32_bf16(qf[mt][0], kf[kt][0], sc[kt], 0, 0, 0);
                    sc[kt] = __builtin_amdgcn_mfma_f32_16x16x32_bf16(qf[mt][1], kf[kt][1], sc[kt], 0, 0, 0);
                }
                const bool full = (c0 + 63 <= mr);
#pragma unroll
                for (int r = 0; r < 4; r++) {
                    const int qg = mr + quad*4 + r;
#pragma unroll
                    for (int kt = 0; kt < 4; kt++) {
                        float s = sc[kt][r];
                        if (!full) {
                            const int kg = c0 + kt*16 + l15;
                            s = (kg <= qg) ? s : NEG_BIG;
                        }
                        const float p = EXP2F(s);
                        sc[kt][r] = p;
                        ps[mt][r] += p;
                    }
                }
                bf16* pw = &Pl[w][0];
#pragma unroll
                for (int kt = 0; kt < 4; kt++)
#pragma unroll
                    for (int r = 0; r < 4; r++)
                        pw[(quad*4 + r)*72 + kt*16 + l15] = __float2bfloat16(sc[kt][r]);
                v8s pf0 = *(const v8s*)&pw[l15*72 + quad*8];
                v8s pf1 = *(const v8s*)&pw[l15*72 + 32 + quad*8];
#pragma unroll
                for (int dt = 0; dt < 4; dt++) {
                    o[mt][dt] = __builtin_amdgcn_mfma_f32_16x16x32_bf16(pf0, vf[dt][0], o[mt][dt], 0, 0, 0);
                    o[mt][dt] = __builtin_amdgcn_mfma_f32_16x16x32_bf16(pf1, vf[dt][1], o[mt][dt], 0, 0, 0);
                }
            }
        }
    }

    const int b_ = bh >> 4, h = bh & 15;
#pragma unroll
    for (int mt = 0; mt < 2; mt++) {
        const int mr = mt ? mrow1 : mrow0;
#pragma unroll
        for (int r = 0; r < 4; r++) {
            float l = ps[mt][r];
#pragma unroll
            for (int off = 1; off < 16; off <<= 1) l += __shfl_xor(l, off);
            const float linv = 1.0f / l;
            const int qg = mr + quad*4 + r;
#pragma unroll
            for (int dt = 0; dt < 4; dt++)
                ctx[(b_*S_ + qg)*D_ + h*HD_ + dt*16 + l15] = __float2bfloat16(o[mt][dt][r] * linv);
        }
    }
}

extern "C" void kernel_launch(void* const* d_in, const int* in_sizes, int n_in,
                              void* d_out, int out_size, void* d_ws, size_t ws_size,
                              hipStream_t stream) {
    const float* x  = (const float*)d_in[0];
    const float* Wq = (const float*)d_in[1];
    const float* Wk = (const float*)d_in[2];
    const float* Wv = (const float*)d_in[3];
    const float* Wo = (const float*)d_in[4];
    const float* bo = (const float*)d_in[5];
    float* out = (float*)d_out;

    const size_t SEG = (size_t)2 * H_ * S_ * HD_;      // 4 Mi bf16 elems = 8 MB
    bf16* qd  = (bf16*)d_ws;
    bf16* kd  = qd  + SEG;
    bf16* vtd = kd  + SEG;
    bf16* xc  = vtd + SEG;                             // x-bf16, later ctx
    bf16* wqb = xc + SEG;
    bf16* wkb = wqb + 1024 * 1024;
    bf16* wvb = wkb + 1024 * 1024;
    bf16* wvv = wvb;                                    // (naming)
    bf16* wob = wvb + 1024 * 1024;
    (void)wvv;

    const size_t need_fast = (4 * SEG + 4 * 1024 * 1024) * sizeof(bf16);   // 40 MB

    if (ws_size >= need_fast) {
        cvt_bf16<<<dim3(2048, 5), 256, 0, stream>>>(x, Wq, Wk, Wv, Wo,
                                                    xc, wqb, wkb, wvb, wob);
        gemm_qkv_f<<<dim3(32, 8, 3), 256, 0, stream>>>(xc, wqb, wkb, wvb, qd, kd, vtd);
        flash_attn<<<dim3(32, 16), 256, 0, stream>>>(qd, kd, vtd, xc);   // xc = ctx
        gemm_out_f<<<dim3(32, 8), 256, 0, stream>>>(xc, wob, bo, out);
    } else {
        gemm_qkv<<<dim3(32, 8, 3), 256, 0, stream>>>(x, Wq, Wk, Wv, qd, kd, vtd);
        flash_attn<<<dim3(32, 16), 256, 0, stream>>>(qd, kd, vtd, xc);
        gemm_out<<<dim3(32, 8), 256, 0, stream>>>(xc, Wo, bo, out);
    }
}